// Round 12
// baseline (331.402 us; speedup 1.0000x reference)
//
#include <hip/hip_runtime.h>
#include <math.h>

typedef __bf16 bf16;
typedef __bf16 bf16x4 __attribute__((ext_vector_type(4)));
typedef __bf16 bf16x8 __attribute__((ext_vector_type(8)));
typedef float f32x4 __attribute__((ext_vector_type(4)));

#define AS1 __attribute__((address_space(1)))
#define AS3 __attribute__((address_space(3)))

__device__ __forceinline__ void gload_lds16(const bf16* g, bf16* l) {
    __builtin_amdgcn_global_load_lds((const AS1 void*)g, (AS3 void*)l, 16, 0, 0);
}

__device__ __forceinline__ float gelu_fast(float v) {
    const float u = 1.5957691216057308f * (v + 0.044715f * v * v * v);
    return v / (1.0f + __expf(-u));
}

// ---------------- all weight transposes + cast in ONE launch
__global__ __launch_bounds__(256)
void wprep_all(const float* __restrict__ qkv_w, const float* __restrict__ proj_w,
               const float* __restrict__ fc1_w, const float* __restrict__ fc2_w,
               bf16* __restrict__ qkv_wt, bf16* __restrict__ proj_wt,
               bf16* __restrict__ fc1_wt, bf16* __restrict__ fc2_wt)
{
    int idx = blockIdx.x * 256 + threadIdx.x;
    const float* src; bf16* dst; int K, N;
    if (idx < 196608)            { src = qkv_w;  dst = qkv_wt;  K = 256;  N = 768; }
    else if (idx < 262144)       { idx -= 196608; src = proj_w; dst = proj_wt; K = 256;  N = 256; }
    else if (idx < 524288)       { idx -= 262144; src = fc1_w;  dst = fc1_wt;  K = 256;  N = 1024; }
    else                         { idx -= 524288; src = fc2_w;  dst = fc2_wt;  K = 1024; N = 256; }
    const int k = idx / N, n = idx % N;
    dst[(long)n * K + k] = (bf16)src[idx];
}

// ---------------- LN1 + cyclic shift(-4,-4) + window partition -> xw bf16 [B*64win][64][256]
__global__ __launch_bounds__(256)
void ln1_window(const float* __restrict__ x, const float* __restrict__ g,
                const float* __restrict__ be, bf16* __restrict__ xw)
{
    const int t = threadIdx.x;
    const int lane = t & 63;
    const int w = t >> 6;
    const long tok = (long)blockIdx.x * 4 + w;
    const float4 v = ((const float4*)(x + tok * 256))[lane];
    float sum = v.x + v.y + v.z + v.w;
    float sq  = v.x * v.x + v.y * v.y + v.z * v.z + v.w * v.w;
#pragma unroll
    for (int m = 32; m >= 1; m >>= 1) {
        sum += __shfl_xor(sum, m, 64);
        sq  += __shfl_xor(sq,  m, 64);
    }
    const float mean = sum * (1.0f / 256.0f);
    const float var  = sq * (1.0f / 256.0f) - mean * mean;
    const float rstd = rsqrtf(var + 1e-5f);
    const float4 gv = ((const float4*)g)[lane];
    const float4 bv = ((const float4*)be)[lane];
    bf16x4 ov;
    ov[0] = (bf16)((v.x - mean) * rstd * gv.x + bv.x);
    ov[1] = (bf16)((v.y - mean) * rstd * gv.y + bv.y);
    ov[2] = (bf16)((v.z - mean) * rstd * gv.z + bv.z);
    ov[3] = (bf16)((v.w - mean) * rstd * gv.w + bv.w);
    const int b = (int)(tok >> 12);
    const int l = (int)(tok & 4095);
    const int i = l >> 6, j = l & 63;
    const int ip = (i + 60) & 63, jp = (j + 60) & 63;   // shifted coords
    const int winl = ((ip >> 3) << 3) + (jp >> 3);
    const int n = ((ip & 7) << 3) + (jp & 7);
    const long drow = ((long)b * 64 + winl) * 64 + n;
    *(bf16x4*)(xw + drow * 256 + lane * 4) = ov;
}

// ---------------- LN2: y = x + proj_out, then layernorm -> xn2 bf16
__global__ __launch_bounds__(256)
void ln2_kernel(const float* __restrict__ x, const bf16* __restrict__ pj,
                const float* __restrict__ g, const float* __restrict__ be,
                bf16* __restrict__ xn2)
{
    const int t = threadIdx.x;
    const int lane = t & 63;
    const int w = t >> 6;
    const long tok = (long)blockIdx.x * 4 + w;
    const float4 xv = ((const float4*)(x + tok * 256))[lane];
    const bf16x4 pv = *(const bf16x4*)(pj + tok * 256 + lane * 4);
    float y0 = xv.x + (float)pv[0];
    float y1 = xv.y + (float)pv[1];
    float y2 = xv.z + (float)pv[2];
    float y3 = xv.w + (float)pv[3];
    float sum = y0 + y1 + y2 + y3;
    float sq  = y0 * y0 + y1 * y1 + y2 * y2 + y3 * y3;
#pragma unroll
    for (int m = 32; m >= 1; m >>= 1) {
        sum += __shfl_xor(sum, m, 64);
        sq  += __shfl_xor(sq,  m, 64);
    }
    const float mean = sum * (1.0f / 256.0f);
    const float var  = sq * (1.0f / 256.0f) - mean * mean;
    const float rstd = rsqrtf(var + 1e-5f);
    const float4 gv = ((const float4*)g)[lane];
    const float4 bv = ((const float4*)be)[lane];
    bf16x4 ov;
    ov[0] = (bf16)((y0 - mean) * rstd * gv.x + bv.x);
    ov[1] = (bf16)((y1 - mean) * rstd * gv.y + bv.y);
    ov[2] = (bf16)((y2 - mean) * rstd * gv.z + bv.z);
    ov[3] = (bf16)((y3 - mean) * rstd * gv.w + bv.w);
    *(bf16x4*)(xn2 + tok * 256 + lane * 4) = ov;
}

// ---------------- GEMM 256x128 tile (QKV / proj) — R11 proven structure.
// EPI 0: +bias -> bf16 qkvb (Q/K via LDS-transpose coalesced path); V -> vT
// EPI 1: +bias -> bf16 out[unwindowed tok*256]  (proj)
template<int EPI, int KT>
__global__ __launch_bounds__(512, 2)
void gemm_w(const bf16* __restrict__ A, const bf16* __restrict__ Bt,
            const float* __restrict__ bias, void* __restrict__ outp,
            int N, const float* __restrict__ xres, void* __restrict__ aux,
            int gx, int nb)
{
    constexpr int K = KT * 32;
    extern __shared__ bf16 lds[];
    bf16* sA = lds;                 // 3 bufs x 8192 elems (256x32)
    bf16* sB = lds + 3 * 8192;      // 3 bufs x 4096 elems (128x32)
    const int t = threadIdx.x;
    const int l = t & 63;
    const int w = t >> 6;
    const int wr = w >> 1, wc = w & 1;
    const int q = nb >> 3;
    const int id = ((int)blockIdx.x & 7) * q + ((int)blockIdx.x >> 3);
    const long m0 = (long)(id / gx) * 256;
    const long n0 = (long)(id % gx) * 128;

    const bf16* asrcp[2]; bf16* adstp[2];
#pragma unroll
    for (int j = 0; j < 2; j++) {
        const int idx = j * 512 + t;
        const int p = idx >> 3, s = idx & 7;
        const int sl = s ^ (p & 7);
        const int row = 2 * p + (sl >> 2);
        const int ce = (sl & 3) * 8;
        asrcp[j] = A + (m0 + row) * (long)K + ce;
        adstp[j] = &sA[idx * 8];
    }
    const bf16* bsrcp; bf16* bdstp;
    {
        const int p = t >> 3, s = t & 7;
        const int sl = s ^ (p & 7);
        const int row = 2 * p + (sl >> 2);
        const int ce = (sl & 3) * 8;
        bsrcp = Bt + (n0 + row) * (long)K + ce;
        bdstp = &sB[t * 8];
    }

    const int c = l >> 4;
    int eA[4], eB[4];
#pragma unroll
    for (int i = 0; i < 4; i++) {
        const int rowA = wr * 64 + (l & 15) + i * 16;
        const int pa = rowA >> 1;
        eA[i] = (pa * 8 + ((((rowA & 1) << 2) + c) ^ (pa & 7))) * 8;
        const int rowB = wc * 64 + (l & 15) + i * 16;
        const int pb = rowB >> 1;
        eB[i] = (pb * 8 + ((((rowB & 1) << 2) + c) ^ (pb & 7))) * 8;
    }

    f32x4 acc[4][4];
#pragma unroll
    for (int i = 0; i < 4; i++)
#pragma unroll
        for (int j = 0; j < 4; j++) acc[i][j] = (f32x4){0.f, 0.f, 0.f, 0.f};

#define STAGE(bufi, ko)                                                        \
    do {                                                                       \
        gload_lds16(asrcp[0] + (ko), adstp[0] + (bufi) * 8192);                \
        gload_lds16(asrcp[1] + (ko), adstp[1] + (bufi) * 8192);                \
        gload_lds16(bsrcp + (ko), bdstp + (bufi) * 4096);                      \
    } while (0)

    STAGE(0, 0);
    STAGE(1, 32);

#pragma unroll
    for (int kt = 0; kt < KT; ++kt) {
        const int buf = kt % 3;
        if (kt < KT - 1)
            asm volatile("s_waitcnt vmcnt(3)" ::: "memory");
        else
            asm volatile("s_waitcnt vmcnt(0)" ::: "memory");
        __builtin_amdgcn_s_barrier();
        __builtin_amdgcn_sched_barrier(0);
        if (kt + 2 < KT)
            STAGE((kt + 2) % 3, (kt + 2) * 32);
        bf16x8 av[4], bv[4];
#pragma unroll
        for (int ni = 0; ni < 4; ni++)
            bv[ni] = *(const bf16x8*)&sB[buf * 4096 + eB[ni]];
#pragma unroll
        for (int mi = 0; mi < 4; mi++)
            av[mi] = *(const bf16x8*)&sA[buf * 8192 + eA[mi]];
#pragma unroll
        for (int mi = 0; mi < 4; mi++)
#pragma unroll
            for (int ni = 0; ni < 4; ni++)
                acc[mi][ni] = __builtin_amdgcn_mfma_f32_16x16x32_bf16(
                    bv[ni], av[mi], acc[mi][ni], 0, 0, 0);
    }
#undef STAGE

    // ---- epilogue ----
    const bool transpose_path = (EPI == 0 && n0 < 512);
    if (transpose_path) {
        __syncthreads();
        char* wlds = (char*)(lds) + w * 8704;     // 64 rows x 136B per wave
#pragma unroll
        for (int mi = 0; mi < 4; mi++)
#pragma unroll
            for (int ni = 0; ni < 4; ni++) {
                const int colb = (ni * 16 + (l >> 4) * 4) * 2;
                const int rowl = mi * 16 + (l & 15);
                const float4 bz = *(const float4*)&bias[n0 + wc * 64 + ni * 16 + (l >> 4) * 4];
                float vv[4];
                vv[0] = acc[mi][ni][0] + bz.x;
                vv[1] = acc[mi][ni][1] + bz.y;
                vv[2] = acc[mi][ni][2] + bz.z;
                vv[3] = acc[mi][ni][3] + bz.w;
                bf16x4 ov;
#pragma unroll
                for (int j = 0; j < 4; j++) ov[j] = (bf16)vv[j];
                *(bf16x4*)(wlds + rowl * 136 + (colb ^ ((rowl & 7) << 4))) = ov;
            }
        bf16* outb = (bf16*)outp;
#pragma unroll
        for (int j = 0; j < 8; j++) {
            const int r = j * 8 + (l >> 3);
            const bf16x8 vr = *(const bf16x8*)(wlds + r * 136 + (((l & 7) * 16) ^ ((r & 7) << 4)));
            const long row = m0 + wr * 64 + r;
            const int col = (int)(n0 + wc * 64 + (l & 7) * 8);
            *(bf16x8*)&outb[row * N + col] = vr;
        }
    } else {
#pragma unroll
        for (int mi = 0; mi < 4; mi++)
#pragma unroll
            for (int ni = 0; ni < 4; ni++) {
                const long row = m0 + wr * 64 + mi * 16 + (l & 15);
                const int col = (int)(n0 + wc * 64 + ni * 16 + (l >> 4) * 4);
                const float4 bz = *(const float4*)&bias[col];
                float vv[4];
                vv[0] = acc[mi][ni][0] + bz.x;
                vv[1] = acc[mi][ni][1] + bz.y;
                vv[2] = acc[mi][ni][2] + bz.z;
                vv[3] = acc[mi][ni][3] + bz.w;
                if constexpr (EPI == 0) {
                    bf16* vt = (bf16*)aux;
                    const int win = (int)(row >> 6);
                    const int n = (int)(row & 63);
#pragma unroll
                    for (int j = 0; j < 4; j++)
                        vt[(long)win * 16384 + (col - 512 + j) * 64 + n] = (bf16)vv[j];
                } else {
                    bf16x4 ov;
#pragma unroll
                    for (int j = 0; j < 4; j++) ov[j] = (bf16)vv[j];
                    const int gwin = (int)(row >> 6);
                    const int n = (int)(row & 63);
                    const int bb = gwin >> 6, wi = gwin & 63;
                    const int ipp = ((wi >> 3) << 3) + (n >> 3);
                    const int jpp = ((wi & 7) << 3) + (n & 7);
                    const int ii = (ipp + 4) & 63, jj = (jpp + 4) & 63;
                    const long tok = ((long)bb << 12) + (ii << 6) + jj;
                    *(bf16x4*)&((bf16*)outp)[tok * 256 + col] = ov;
                }
            }
    }
    (void)xres; (void)aux;
}

// ---------------- FUSED MLP: out = x + (GELU(xn2@W1+b1))@W2 + b2
// 512 blocks x 512 thr; block owns 128 rows. X-tile resident in LDS (64KB,
// swizzled); 8 hidden-chunks of 128: phase1 H=GELU(X@W1chunk) -> H in LDS
// (128 rows x 272B padded, conflict-free); phase2 out_acc += H@W2chunk.
// One 96-step counted-vmcnt pipeline over W tiles (3-buf); no global stores
// inside the loop (vmcnt counts stay exact); lgkmcnt(0) before every barrier
// covers H write->read->write hazards. Final epilogue: +b2 +x -> f32 out.
__global__ __launch_bounds__(512, 2)
void fused_mlp(const bf16* __restrict__ xn2, const bf16* __restrict__ w1t,
               const bf16* __restrict__ w2t, const float* __restrict__ b1,
               const float* __restrict__ b2, const float* __restrict__ xres,
               float* __restrict__ out, int nb)
{
    extern __shared__ bf16 lds[];
    bf16* sX = lds;                          // 32768 elems (8 ktiles x 128x32)
    bf16* sW = lds + 32768;                  // 3 bufs x 8192 elems
    char* sH = (char*)(lds + 32768 + 24576); // 128 rows x 272 B
    const int t = threadIdx.x;
    const int l = t & 63;
    const int w = t >> 6;
    const int wr = w >> 2, wc = w & 3;       // 2 x 4 wave grid
    const int q = nb >> 3;
    const int id = ((int)blockIdx.x & 7) * q + ((int)blockIdx.x >> 3);
    const long m0 = (long)id * 128;

    // ---- staging address precompute ----
    // W1 tile (128 N-rows x 32 k): 512 chunks, 1/thread
    const bf16* w1base; bf16* w1dst;
    {
        const int p = t >> 3, s = t & 7;
        const int sl = s ^ (p & 7);
        const int row = 2 * p + (sl >> 2);
        const int ce = (sl & 3) * 8;
        w1base = w1t + (long)row * 256 + ce;
        w1dst = sW + t * 8;
    }
    // W2 tile (256 N-rows x 32 k): 1024 chunks, 2/thread
    const bf16* w2base[2]; bf16* w2dst[2];
#pragma unroll
    for (int j = 0; j < 2; j++) {
        const int cc = j * 512 + t;
        const int p = cc >> 3, s = cc & 7;
        const int sl = s ^ (p & 7);
        const int row = 2 * p + (sl >> 2);
        const int ce = (sl & 3) * 8;
        w2base[j] = w2t + (long)row * 1024 + ce;
        w2dst[j] = sW + cc * 8;
    }

    // ---- fragment read offsets ----
    const int c = l >> 4;
    int eXA[4], eB1[2], eB2[4], hrA[4], hwOf[4][2];
#pragma unroll
    for (int i = 0; i < 4; i++) {
        const int row = wr * 64 + i * 16 + (l & 15);
        const int p = row >> 1;
        eXA[i] = (p * 8 + ((((row & 1) << 2) + c) ^ (p & 7))) * 8;
        hrA[i] = row * 272 + c * 16;
#pragma unroll
        for (int nj = 0; nj < 2; nj++)
            hwOf[i][nj] = row * 272 + (wc * 32 + nj * 16 + (l >> 4) * 4) * 2;
    }
#pragma unroll
    for (int nj = 0; nj < 2; nj++) {
        const int brow = wc * 32 + nj * 16 + (l & 15);
        const int p = brow >> 1;
        eB1[nj] = (p * 8 + ((((brow & 1) << 2) + c) ^ (p & 7))) * 8;
    }
#pragma unroll
    for (int nj = 0; nj < 4; nj++) {
        const int brow = wc * 64 + nj * 16 + (l & 15);
        const int p = brow >> 1;
        eB2[nj] = (p * 8 + ((((brow & 1) << 2) + c) ^ (p & 7))) * 8;
    }

    // ---- prologue: stage X (8 loads/thread) + first two W1 tiles ----
    {
#pragma unroll
        for (int j = 0; j < 8; j++) {
            const int idx = j * 512 + t;
            const int kt = idx >> 9, cc = idx & 511;
            const int p = cc >> 3, s = cc & 7;
            const int sl = s ^ (p & 7);
            const int row = 2 * p + (sl >> 2);
            const int ce = (sl & 3) * 8;
            gload_lds16(xn2 + (m0 + row) * 256 + kt * 32 + ce, sX + kt * 4096 + cc * 8);
        }
    }
#define STAGE_P1(hc_, kt_, buf_) \
    gload_lds16(w1base + (hc_) * 32768 + (kt_) * 32, w1dst + (buf_) * 8192)
#define STAGE_P2(hc_, kt2_, buf_)                                              \
    do {                                                                       \
        gload_lds16(w2base[0] + (hc_) * 128 + (kt2_) * 32, w2dst[0] + (buf_) * 8192); \
        gload_lds16(w2base[1] + (hc_) * 128 + (kt2_) * 32, w2dst[1] + (buf_) * 8192); \
    } while (0)
#define STAGE_G(g_)                                                            \
    do {                                                                       \
        if ((g_) < 96) {                                                       \
            if (((g_) % 12) < 8) STAGE_P1((g_) / 12, (g_) % 12, (g_) % 3);     \
            else STAGE_P2((g_) / 12, (g_) % 12 - 8, (g_) % 3);                 \
        }                                                                      \
    } while (0)
#define PIPE_WAIT(gn_)                                                         \
    do {                                                                       \
        if ((gn_) >= 96)                                                       \
            asm volatile("s_waitcnt vmcnt(0) lgkmcnt(0)" ::: "memory");        \
        else if (((gn_) % 12) < 8)                                             \
            asm volatile("s_waitcnt vmcnt(1) lgkmcnt(0)" ::: "memory");        \
        else                                                                   \
            asm volatile("s_waitcnt vmcnt(2) lgkmcnt(0)" ::: "memory");        \
    } while (0)

    STAGE_P1(0, 0, 0);
    STAGE_P1(0, 1, 1);

    f32x4 acc[4][4];
#pragma unroll
    for (int i = 0; i < 4; i++)
#pragma unroll
        for (int j = 0; j < 4; j++) acc[i][j] = (f32x4){0.f, 0.f, 0.f, 0.f};

#pragma unroll
    for (int hc = 0; hc < 8; hc++) {
        f32x4 acc1[4][2];
#pragma unroll
        for (int i = 0; i < 4; i++)
#pragma unroll
            for (int j = 0; j < 2; j++) acc1[i][j] = (f32x4){0.f, 0.f, 0.f, 0.f};

        // ---- phase 1: H = X @ W1chunk (8 k-steps) ----
#pragma unroll
        for (int kt = 0; kt < 8; kt++) {
            const int g = hc * 12 + kt;
            PIPE_WAIT(g + 1);
            __builtin_amdgcn_s_barrier();
            __builtin_amdgcn_sched_barrier(0);
            STAGE_G(g + 2);
            const int buf = g % 3;
            bf16x8 b0 = *(const bf16x8*)&sW[buf * 8192 + eB1[0]];
            bf16x8 b1 = *(const bf16x8*)&sW[buf * 8192 + eB1[1]];
#pragma unroll
            for (int mi = 0; mi < 4; mi++) {
                const bf16x8 av = *(const bf16x8*)&sX[kt * 4096 + eXA[mi]];
                acc1[mi][0] = __builtin_amdgcn_mfma_f32_16x16x32_bf16(b0, av, acc1[mi][0], 0, 0, 0);
                acc1[mi][1] = __builtin_amdgcn_mfma_f32_16x16x32_bf16(b1, av, acc1[mi][1], 0, 0, 0);
            }
        }
        // ---- phase-1 epilogue: bias + GELU -> H in LDS ----
#pragma unroll
        for (int mi = 0; mi < 4; mi++)
#pragma unroll
            for (int nj = 0; nj < 2; nj++) {
                const int hcol = wc * 32 + nj * 16 + (l >> 4) * 4;
                const float4 bz = *(const float4*)&b1[hc * 128 + hcol];
                bf16x4 hv;
                hv[0] = (bf16)gelu_fast(acc1[mi][nj][0] + bz.x);
                hv[1] = (bf16)gelu_fast(acc1[mi][nj][1] + bz.y);
                hv[2] = (bf16)gelu_fast(acc1[mi][nj][2] + bz.z);
                hv[3] = (bf16)gelu_fast(acc1[mi][nj][3] + bz.w);
                *(bf16x4*)(sH + hwOf[mi][nj]) = hv;
            }
        // ---- phase 2: out_acc += H @ W2chunk (4 k-steps) ----
#pragma unroll
        for (int kt2 = 0; kt2 < 4; kt2++) {
            const int g = hc * 12 + 8 + kt2;
            PIPE_WAIT(g + 1);
            __builtin_amdgcn_s_barrier();
            __builtin_amdgcn_sched_barrier(0);
            STAGE_G(g + 2);
            const int buf = g % 3;
            bf16x8 bb[4];
#pragma unroll
            for (int nj = 0; nj < 4; nj++)
                bb[nj] = *(const bf16x8*)&sW[buf * 8192 + eB2[nj]];
#pragma unroll
            for (int mi = 0; mi < 4; mi++) {
                const bf16x8 av = *(const bf16x8*)(sH + hrA[mi] + kt2 * 64);
#pragma unroll
                for (int nj = 0; nj < 4; nj++)
                    acc[mi][nj] = __builtin_amdgcn_mfma_f32_16x16x32_bf16(bb[nj], av, acc[mi][nj], 0, 0, 0);
            }
        }
    }
#undef STAGE_P1
#undef STAGE_P2
#undef STAGE_G
#undef PIPE_WAIT

    // ---- final epilogue: +b2 + x residual -> f32 out ----
#pragma unroll
    for (int mi = 0; mi < 4; mi++)
#pragma unroll
        for (int nj = 0; nj < 4; nj++) {
            const long row = m0 + wr * 64 + mi * 16 + (l & 15);
            const int col = wc * 64 + nj * 16 + (l >> 4) * 4;
            const float4 bz = *(const float4*)&b2[col];
            const float4 xr = *(const float4*)&xres[row * 256 + col];
            float4 ov;
            ov.x = acc[mi][nj][0] + bz.x + xr.x;
            ov.y = acc[mi][nj][1] + bz.y + xr.y;
            ov.z = acc[mi][nj][2] + bz.z + xr.z;
            ov.w = acc[mi][nj][3] + bz.w + xr.w;
            *(float4*)&out[row * 256 + col] = ov;
        }
}

// ---------------- per-window attention (R8/R9 proven)
__global__ __launch_bounds__(256, 4)
void attn_kernel(const bf16* __restrict__ qkv, const bf16* __restrict__ vT,
                 const float* __restrict__ rpb, bf16* __restrict__ out)
{
    __shared__ bf16 P_lds[4][64 * 64];
    const int t = threadIdx.x;
    const int lane = t & 63;
    const int w = t >> 6;
    const int win = blockIdx.x >> 1;
    const int head = (blockIdx.x & 1) * 4 + w;
    const int wi = win & 63;
    const int lr = lane & 15;
    const int lg = lane >> 4;
    const int lk = lg * 8;
    const long base = (long)win * 64 * 768;
    const float scale = 0.17677669529663687f;   // 32^-0.5
    const int whb = (wi >> 3) << 3;
    const int wwb = (wi & 7) << 3;
    const f32x4 z4 = {0.f, 0.f, 0.f, 0.f};

    const bf16* qp  = qkv + base + head * 32;
    const bf16* kp  = qkv + base + 256 + head * 32;
    const bf16* vtp = vT + (long)win * 16384 + head * 32 * 64;

    int idm[4];
#pragma unroll
    for (int ni = 0; ni < 4; ni++) {
        const int m = ni * 16 + lr;
        const int gi2 = whb + (m >> 3), gj2 = wwb + (m & 7);
        idm[ni] = (gi2 < 56 ? 0 : (gi2 < 60 ? 1 : 2)) * 3 + (gj2 < 56 ? 0 : (gj2 < 60 ? 1 : 2));
    }

    bf16x8 aq[4], bk[4];
#pragma unroll
    for (int mi = 0; mi < 4; mi++)
        aq[mi] = *(const bf16x8*)(qp + (mi * 16 + lr) * 768 + lk);
#pragma unroll
    for (int ni = 0; ni < 4; ni++)
        bk[ni] = *(const bf16x8*)(kp + (ni * 16 + lr) * 768 + lk);

    f32x4 s[4][4];
#pragma unroll
    for (int i = 0; i < 4; i++)
#pragma unroll
        for (int j = 0; j < 4; j++) s[i][j] = z4;
#pragma unroll
    for (int mi = 0; mi < 4; mi++)
#pragma unroll
        for (int ni = 0; ni < 4; ni++)
            s[mi][ni] = __builtin_amdgcn_mfma_f32_16x16x32_bf16(aq[mi], bk[ni], s[mi][ni], 0, 0, 0);

#pragma unroll
    for (int mi = 0; mi < 4; mi++)
#pragma unroll
        for (int r = 0; r < 4; r++) {
            const int n = mi * 16 + lg * 4 + r;
            const int gi = whb + (n >> 3);
            const int gj = wwb + (n & 7);
            const int idn = (gi < 56 ? 0 : (gi < 60 ? 1 : 2)) * 3 + (gj < 56 ? 0 : (gj < 60 ? 1 : 2));
            float vals[4];
            float rowmax = -3.0e38f;
#pragma unroll
            for (int ni = 0; ni < 4; ni++) {
                const int m = ni * 16 + lr;
                const int dj = (n & 7) - (m & 7);
                const int di = (n >> 3) - (m >> 3);
                float sv = s[mi][ni][r] * scale + rpb[((dj + 7) * 15 + (di + 7)) * 8 + head];
                if (idn == idm[ni]) sv -= 100.0f;   // faithful: -100 where EQUAL
                vals[ni] = sv;
                rowmax = fmaxf(rowmax, sv);
            }
#pragma unroll
            for (int msk = 8; msk >= 1; msk >>= 1)
                rowmax = fmaxf(rowmax, __shfl_xor(rowmax, msk, 64));
            float rsum = 0.f;
#pragma unroll
            for (int ni = 0; ni < 4; ni++) {
                const float p = __expf(vals[ni] - rowmax);
                vals[ni] = p;
                rsum += p;
            }
#pragma unroll
            for (int msk = 8; msk >= 1; msk >>= 1)
                rsum += __shfl_xor(rsum, msk, 64);
            const float inv = 1.0f / rsum;
            const int swz = (n & 7) << 3;
#pragma unroll
            for (int ni = 0; ni < 4; ni++)
                P_lds[w][n * 64 + ((ni * 16 + lr) ^ swz)] = (bf16)(vals[ni] * inv);
        }

    f32x4 o[4][2];
#pragma unroll
    for (int i = 0; i < 4; i++)
#pragma unroll
        for (int j = 0; j < 2; j++) o[i][j] = z4;
#pragma unroll
    for (int kk = 0; kk < 2; kk++) {
        bf16x8 bv[2];
#pragma unroll
        for (int ni = 0; ni < 2; ni++)
            bv[ni] = *(const bf16x8*)&vtp[(ni * 16 + lr) * 64 + kk * 32 + lk];
#pragma unroll
        for (int mi = 0; mi < 4; mi++) {
            const int row = mi * 16 + lr;
            const bf16x8 ap = *(const bf16x8*)&P_lds[w][row * 64 + ((kk * 32 + lk) ^ ((row & 7) << 3))];
#pragma unroll
            for (int ni = 0; ni < 2; ni++)
                o[mi][ni] = __builtin_amdgcn_mfma_f32_16x16x32_bf16(bv[ni], ap, o[mi][ni], 0, 0, 0);
        }
    }
#pragma unroll
    for (int mi = 0; mi < 4; mi++)
#pragma unroll
        for (int ni = 0; ni < 2; ni++) {
            const int n = mi * 16 + lr;
            const int d = ni * 16 + lg * 4;
            bf16x4 ov;
            ov[0] = (bf16)o[mi][ni][0]; ov[1] = (bf16)o[mi][ni][1];
            ov[2] = (bf16)o[mi][ni][2]; ov[3] = (bf16)o[mi][ni][3];
            *(bf16x4*)(out + ((long)(win * 64 + n)) * 256 + head * 32 + d) = ov;
        }
}

extern "C" void kernel_launch(void* const* d_in, const int* in_sizes, int n_in,
                              void* d_out, int out_size, void* d_ws, size_t ws_size,
                              hipStream_t stream)
{
    (void)in_sizes; (void)n_in; (void)out_size;
    const float* x      = (const float*)d_in[0];
    const float* n1g    = (const float*)d_in[1];
    const float* n1b    = (const float*)d_in[2];
    const float* qkv_w  = (const float*)d_in[3];
    const float* qkv_b  = (const float*)d_in[4];
    const float* rpb    = (const float*)d_in[5];
    const float* proj_w = (const float*)d_in[6];
    const float* proj_b = (const float*)d_in[7];
    const float* n2g    = (const float*)d_in[8];
    const float* n2b    = (const float*)d_in[9];
    const float* fc1_w  = (const float*)d_in[10];
    const float* fc1_b  = (const float*)d_in[11];
    const float* fc2_w  = (const float*)d_in[12];
    const float* fc2_b  = (const float*)d_in[13];
    float* out = (float*)d_out;

    // workspace plan (130 MB):
    //   0..2MB weights | 2..34MB xw -> attn_o -> xn2 | 34..130MB qkvb -> proj_o
    //   vT (32MB) staged in d_out during QKV+attn (dead before fused_mlp writes out)
    char* ws = (char*)d_ws;
    bf16* qkv_wt  = (bf16*)(ws + 0);          // 768x256
    bf16* proj_wt = (bf16*)(ws + 393216);     // 256x256
    bf16* fc1_wt  = (bf16*)(ws + 524288);     // 1024x256
    bf16* fc2_wt  = (bf16*)(ws + 1048576);    // 256x1024
    bf16* xw      = (bf16*)(ws + 2097152);    // 32MB  [65536][256]
    bf16* qkvb    = (bf16*)(ws + 35651584);   // 96MB  [65536][768] (V cols unused)
    bf16* attn_o  = xw;                       // reuse xw (dead after QKV gemm)
    bf16* proj_o  = qkvb;                     // reuse qkvb (dead after attn)
    bf16* vT      = (bf16*)d_out;             // V^T staging in d_out
    bf16* xn2     = xw;                       // LN2 out in ws (attn_o dead after proj)
    if (ws_size < 136314880ull) return;       // insufficient scratch

    const size_t LB  = 73728;   // 72 KB (256x128 3-stage)
    const size_t LBM = 149504;  // fused MLP: X 64K + W 48K + H 34K

    wprep_all<<<3072, 256, 0, stream>>>(qkv_w, proj_w, fc1_w, fc2_w,
                                        qkv_wt, proj_wt, fc1_wt, fc2_wt);

    ln1_window<<<16384, 256, 0, stream>>>(x, n1g, n1b, xw);
    gemm_w<0, 8><<<1536, 512, LB, stream>>>(xw, qkv_wt, qkv_b, qkvb, 768, nullptr, vT, 6, 1536);
    attn_kernel<<<2048, 256, 0, stream>>>(qkvb, vT, rpb, attn_o);
    gemm_w<1, 8><<<512, 512, LB, stream>>>(attn_o, proj_wt, proj_b, proj_o, 256, nullptr, nullptr, 2, 512);
    ln2_kernel<<<16384, 256, 0, stream>>>(x, proj_o, n2g, n2b, xn2);
    fused_mlp<<<512, 512, LBM, stream>>>(xn2, fc1_wt, fc2_wt, fc1_b, fc2_b, x, out, 512);
}

// Round 13
// 281.444 us; speedup vs baseline: 1.1775x; 1.1775x over previous
//
#include <hip/hip_runtime.h>
#include <math.h>

typedef __bf16 bf16;
typedef __bf16 bf16x4 __attribute__((ext_vector_type(4)));
typedef __bf16 bf16x8 __attribute__((ext_vector_type(8)));
typedef float f32x4 __attribute__((ext_vector_type(4)));

#define AS1 __attribute__((address_space(1)))
#define AS3 __attribute__((address_space(3)))

__device__ __forceinline__ void gload_lds16(const bf16* g, bf16* l) {
    __builtin_amdgcn_global_load_lds((const AS1 void*)g, (AS3 void*)l, 16, 0, 0);
}

__device__ __forceinline__ float gelu_fast(float v) {
    const float u = 1.5957691216057308f * (v + 0.044715f * v * v * v);
    return v / (1.0f + __expf(-u));
}

// ---------------- all weight transposes + cast in ONE launch
__global__ __launch_bounds__(256)
void wprep_all(const float* __restrict__ qkv_w, const float* __restrict__ proj_w,
               const float* __restrict__ fc1_w, const float* __restrict__ fc2_w,
               bf16* __restrict__ qkv_wt, bf16* __restrict__ proj_wt,
               bf16* __restrict__ fc1_wt, bf16* __restrict__ fc2_wt)
{
    int idx = blockIdx.x * 256 + threadIdx.x;
    const float* src; bf16* dst; int K, N;
    if (idx < 196608)            { src = qkv_w;  dst = qkv_wt;  K = 256;  N = 768; }
    else if (idx < 262144)       { idx -= 196608; src = proj_w; dst = proj_wt; K = 256;  N = 256; }
    else if (idx < 524288)       { idx -= 262144; src = fc1_w;  dst = fc1_wt;  K = 256;  N = 1024; }
    else                         { idx -= 524288; src = fc2_w;  dst = fc2_wt;  K = 1024; N = 256; }
    const int k = idx / N, n = idx % N;
    dst[(long)n * K + k] = (bf16)src[idx];
}

// ---------------- LN1 + cyclic shift(-4,-4) + window partition -> xw bf16 [B*64win][64][256]
__global__ __launch_bounds__(256)
void ln1_window(const float* __restrict__ x, const float* __restrict__ g,
                const float* __restrict__ be, bf16* __restrict__ xw)
{
    const int t = threadIdx.x;
    const int lane = t & 63;
    const int w = t >> 6;
    const long tok = (long)blockIdx.x * 4 + w;
    const float4 v = ((const float4*)(x + tok * 256))[lane];
    float sum = v.x + v.y + v.z + v.w;
    float sq  = v.x * v.x + v.y * v.y + v.z * v.z + v.w * v.w;
#pragma unroll
    for (int m = 32; m >= 1; m >>= 1) {
        sum += __shfl_xor(sum, m, 64);
        sq  += __shfl_xor(sq,  m, 64);
    }
    const float mean = sum * (1.0f / 256.0f);
    const float var  = sq * (1.0f / 256.0f) - mean * mean;
    const float rstd = rsqrtf(var + 1e-5f);
    const float4 gv = ((const float4*)g)[lane];
    const float4 bv = ((const float4*)be)[lane];
    bf16x4 ov;
    ov[0] = (bf16)((v.x - mean) * rstd * gv.x + bv.x);
    ov[1] = (bf16)((v.y - mean) * rstd * gv.y + bv.y);
    ov[2] = (bf16)((v.z - mean) * rstd * gv.z + bv.z);
    ov[3] = (bf16)((v.w - mean) * rstd * gv.w + bv.w);
    const int b = (int)(tok >> 12);
    const int l = (int)(tok & 4095);
    const int i = l >> 6, j = l & 63;
    const int ip = (i + 60) & 63, jp = (j + 60) & 63;   // shifted coords
    const int winl = ((ip >> 3) << 3) + (jp >> 3);
    const int n = ((ip & 7) << 3) + (jp & 7);
    const long drow = ((long)b * 64 + winl) * 64 + n;
    *(bf16x4*)(xw + drow * 256 + lane * 4) = ov;
}

// ---------------- GEMM 256x128 tile (QKV / FC1 / FC2) — R11 proven structure.
// EPI 0: +bias -> bf16 qkvb (Q/K via LDS-transpose coalesced path); V -> vT
// EPI 2: +bias, fast GELU -> bf16 out via transpose path (FC1)
// EPI 3: +bias + x residual -> f32 out          (FC2)
template<int EPI, int KT>
__global__ __launch_bounds__(512, 2)
void gemm_w(const bf16* __restrict__ A, const bf16* __restrict__ Bt,
            const float* __restrict__ bias, void* __restrict__ outp,
            int N, const float* __restrict__ xres, void* __restrict__ aux,
            int gx, int nb)
{
    constexpr int K = KT * 32;
    extern __shared__ bf16 lds[];
    bf16* sA = lds;                 // 3 bufs x 8192 elems (256x32)
    bf16* sB = lds + 3 * 8192;      // 3 bufs x 4096 elems (128x32)
    const int t = threadIdx.x;
    const int l = t & 63;
    const int w = t >> 6;
    const int wr = w >> 1, wc = w & 1;
    const int q = nb >> 3;
    const int id = ((int)blockIdx.x & 7) * q + ((int)blockIdx.x >> 3);
    const long m0 = (long)(id / gx) * 256;
    const long n0 = (long)(id % gx) * 128;

    const bf16* asrcp[2]; bf16* adstp[2];
#pragma unroll
    for (int j = 0; j < 2; j++) {
        const int idx = j * 512 + t;
        const int p = idx >> 3, s = idx & 7;
        const int sl = s ^ (p & 7);
        const int row = 2 * p + (sl >> 2);
        const int ce = (sl & 3) * 8;
        asrcp[j] = A + (m0 + row) * (long)K + ce;
        adstp[j] = &sA[idx * 8];
    }
    const bf16* bsrcp; bf16* bdstp;
    {
        const int p = t >> 3, s = t & 7;
        const int sl = s ^ (p & 7);
        const int row = 2 * p + (sl >> 2);
        const int ce = (sl & 3) * 8;
        bsrcp = Bt + (n0 + row) * (long)K + ce;
        bdstp = &sB[t * 8];
    }

    const int c = l >> 4;
    int eA[4], eB[4];
#pragma unroll
    for (int i = 0; i < 4; i++) {
        const int rowA = wr * 64 + (l & 15) + i * 16;
        const int pa = rowA >> 1;
        eA[i] = (pa * 8 + ((((rowA & 1) << 2) + c) ^ (pa & 7))) * 8;
        const int rowB = wc * 64 + (l & 15) + i * 16;
        const int pb = rowB >> 1;
        eB[i] = (pb * 8 + ((((rowB & 1) << 2) + c) ^ (pb & 7))) * 8;
    }

    f32x4 acc[4][4];
#pragma unroll
    for (int i = 0; i < 4; i++)
#pragma unroll
        for (int j = 0; j < 4; j++) acc[i][j] = (f32x4){0.f, 0.f, 0.f, 0.f};

#define STAGE(bufi, ko)                                                        \
    do {                                                                       \
        gload_lds16(asrcp[0] + (ko), adstp[0] + (bufi) * 8192);                \
        gload_lds16(asrcp[1] + (ko), adstp[1] + (bufi) * 8192);                \
        gload_lds16(bsrcp + (ko), bdstp + (bufi) * 4096);                      \
    } while (0)

    STAGE(0, 0);
    STAGE(1, 32);

#pragma unroll
    for (int kt = 0; kt < KT; ++kt) {
        const int buf = kt % 3;
        if (kt < KT - 1)
            asm volatile("s_waitcnt vmcnt(3)" ::: "memory");
        else
            asm volatile("s_waitcnt vmcnt(0)" ::: "memory");
        __builtin_amdgcn_s_barrier();
        __builtin_amdgcn_sched_barrier(0);
        if (kt + 2 < KT)
            STAGE((kt + 2) % 3, (kt + 2) * 32);
        bf16x8 av[4], bv[4];
#pragma unroll
        for (int ni = 0; ni < 4; ni++)
            bv[ni] = *(const bf16x8*)&sB[buf * 4096 + eB[ni]];
#pragma unroll
        for (int mi = 0; mi < 4; mi++)
            av[mi] = *(const bf16x8*)&sA[buf * 8192 + eA[mi]];
#pragma unroll
        for (int mi = 0; mi < 4; mi++)
#pragma unroll
            for (int ni = 0; ni < 4; ni++)
                acc[mi][ni] = __builtin_amdgcn_mfma_f32_16x16x32_bf16(
                    bv[ni], av[mi], acc[mi][ni], 0, 0, 0);
    }
#undef STAGE

    // ---- epilogue ----
    const bool transpose_path = (EPI == 2) || (EPI == 0 && n0 < 512);
    if (transpose_path) {
        __syncthreads();
        char* wlds = (char*)(lds) + w * 8704;     // 64 rows x 136B per wave
#pragma unroll
        for (int mi = 0; mi < 4; mi++)
#pragma unroll
            for (int ni = 0; ni < 4; ni++) {
                const int colb = (ni * 16 + (l >> 4) * 4) * 2;
                const int rowl = mi * 16 + (l & 15);
                const float4 bz = *(const float4*)&bias[n0 + wc * 64 + ni * 16 + (l >> 4) * 4];
                float vv[4];
                vv[0] = acc[mi][ni][0] + bz.x;
                vv[1] = acc[mi][ni][1] + bz.y;
                vv[2] = acc[mi][ni][2] + bz.z;
                vv[3] = acc[mi][ni][3] + bz.w;
                if constexpr (EPI == 2) {
#pragma unroll
                    for (int j = 0; j < 4; j++) vv[j] = gelu_fast(vv[j]);
                }
                bf16x4 ov;
#pragma unroll
                for (int j = 0; j < 4; j++) ov[j] = (bf16)vv[j];
                *(bf16x4*)(wlds + rowl * 136 + (colb ^ ((rowl & 7) << 4))) = ov;
            }
        bf16* outb = (bf16*)outp;
#pragma unroll
        for (int j = 0; j < 8; j++) {
            const int r = j * 8 + (l >> 3);
            const bf16x8 vr = *(const bf16x8*)(wlds + r * 136 + (((l & 7) * 16) ^ ((r & 7) << 4)));
            const long row = m0 + wr * 64 + r;
            const int col = (int)(n0 + wc * 64 + (l & 7) * 8);
            *(bf16x8*)&outb[row * N + col] = vr;
        }
    } else {
#pragma unroll
        for (int mi = 0; mi < 4; mi++)
#pragma unroll
            for (int ni = 0; ni < 4; ni++) {
                const long row = m0 + wr * 64 + mi * 16 + (l & 15);
                const int col = (int)(n0 + wc * 64 + ni * 16 + (l >> 4) * 4);
                const float4 bz = *(const float4*)&bias[col];
                float vv[4];
                vv[0] = acc[mi][ni][0] + bz.x;
                vv[1] = acc[mi][ni][1] + bz.y;
                vv[2] = acc[mi][ni][2] + bz.z;
                vv[3] = acc[mi][ni][3] + bz.w;
                if constexpr (EPI == 3) {
                    const float4 xr = *(const float4*)&xres[row * N + col];
                    float4 ov = {vv[0] + xr.x, vv[1] + xr.y, vv[2] + xr.z, vv[3] + xr.w};
                    *(float4*)&((float*)outp)[row * N + col] = ov;
                } else if constexpr (EPI == 0) {
                    // V columns -> vT[win][d][key] (transposed scalar stores)
                    bf16* vt = (bf16*)aux;
                    const int win = (int)(row >> 6);
                    const int n = (int)(row & 63);
#pragma unroll
                    for (int j = 0; j < 4; j++)
                        vt[(long)win * 16384 + (col - 512 + j) * 64 + n] = (bf16)vv[j];
                }
            }
    }
    (void)xres; (void)aux;
}

// ---------------- FUSED proj + LN2: xn2[tok] = LN(x[tok] + attn_o@Wp + bp)
// 512 blocks x 512 thr; tile = 128 windowed rows x FULL 256 cols (block owns
// complete tokens). K-loop: proven 3-stage counted pipeline (3 loads/thr/step).
// Epilogue: y in fp32 registers; row stats via shfl_xor(16,32) + padded-LDS
// cross-wave reduce; writes bf16 xn2 in TOKEN order (window-reverse + roll+4).
__global__ __launch_bounds__(512, 2)
void proj_ln2(const bf16* __restrict__ A, const bf16* __restrict__ Bt,
              const float* __restrict__ bias, const float* __restrict__ x,
              const float* __restrict__ g2, const float* __restrict__ b2,
              bf16* __restrict__ xn2, int nb)
{
    extern __shared__ bf16 lds[];
    bf16* sA = lds;                       // 3 bufs x 4096 elems (128x32)
    bf16* sB = lds + 3 * 4096;            // 3 bufs x 8192 elems (256x32)
    float* sred = (float*)(lds + 3 * 4096 + 3 * 8192);   // [128][9] floats
    const int t = threadIdx.x;
    const int l = t & 63;
    const int w = t >> 6;
    const int wr = w >> 2, wc = w & 3;    // 2 x 4 wave grid; wave = 64r x 64c
    const int q = nb >> 3;
    const int id = ((int)blockIdx.x & 7) * q + ((int)blockIdx.x >> 3);
    const long m0 = (long)id * 128;

    const bf16* asrcp; bf16* adstp;
    {
        const int p = t >> 3, s = t & 7;
        const int sl = s ^ (p & 7);
        const int row = 2 * p + (sl >> 2);
        const int ce = (sl & 3) * 8;
        asrcp = A + (m0 + row) * 256 + ce;
        adstp = &sA[t * 8];
    }
    const bf16* bsrcp[2]; bf16* bdstp[2];
#pragma unroll
    for (int j = 0; j < 2; j++) {
        const int idx = j * 512 + t;
        const int p = idx >> 3, s = idx & 7;
        const int sl = s ^ (p & 7);
        const int row = 2 * p + (sl >> 2);
        const int ce = (sl & 3) * 8;
        bsrcp[j] = Bt + (long)row * 256 + ce;
        bdstp[j] = &sB[idx * 8];
    }

    const int c = l >> 4;
    int eA[4], eB[4];
#pragma unroll
    for (int i = 0; i < 4; i++) {
        const int rowA = wr * 64 + (l & 15) + i * 16;
        const int pa = rowA >> 1;
        eA[i] = (pa * 8 + ((((rowA & 1) << 2) + c) ^ (pa & 7))) * 8;
        const int rowB = wc * 64 + (l & 15) + i * 16;
        const int pb = rowB >> 1;
        eB[i] = (pb * 8 + ((((rowB & 1) << 2) + c) ^ (pb & 7))) * 8;
    }

    f32x4 acc[4][4];
#pragma unroll
    for (int i = 0; i < 4; i++)
#pragma unroll
        for (int j = 0; j < 4; j++) acc[i][j] = (f32x4){0.f, 0.f, 0.f, 0.f};

#define STAGE(bufi, ko)                                                        \
    do {                                                                       \
        gload_lds16(asrcp + (ko), adstp + (bufi) * 4096);                      \
        gload_lds16(bsrcp[0] + (ko), bdstp[0] + (bufi) * 8192);                \
        gload_lds16(bsrcp[1] + (ko), bdstp[1] + (bufi) * 8192);                \
    } while (0)

    STAGE(0, 0);
    STAGE(1, 32);

#pragma unroll
    for (int kt = 0; kt < 8; ++kt) {
        const int buf = kt % 3;
        if (kt < 7)
            asm volatile("s_waitcnt vmcnt(3)" ::: "memory");
        else
            asm volatile("s_waitcnt vmcnt(0)" ::: "memory");
        __builtin_amdgcn_s_barrier();
        __builtin_amdgcn_sched_barrier(0);
        if (kt + 2 < 8)
            STAGE((kt + 2) % 3, (kt + 2) * 32);
        bf16x8 av[4], bv[4];
#pragma unroll
        for (int ni = 0; ni < 4; ni++)
            bv[ni] = *(const bf16x8*)&sB[buf * 8192 + eB[ni]];
#pragma unroll
        for (int mi = 0; mi < 4; mi++)
            av[mi] = *(const bf16x8*)&sA[buf * 4096 + eA[mi]];
#pragma unroll
        for (int mi = 0; mi < 4; mi++)
#pragma unroll
            for (int ni = 0; ni < 4; ni++)
                acc[mi][ni] = __builtin_amdgcn_mfma_f32_16x16x32_bf16(
                    bv[ni], av[mi], acc[mi][ni], 0, 0, 0);
    }
#undef STAGE

    // ---- epilogue: y = x[tok] + proj + bias; LN over 256 cols; write xn2 ----
    float ts[4] = {0.f, 0.f, 0.f, 0.f}, tq[4] = {0.f, 0.f, 0.f, 0.f};
    long tok[4];
#pragma unroll
    for (int mi = 0; mi < 4; mi++) {
        const long row = m0 + wr * 64 + mi * 16 + (l & 15);
        const int gwin = (int)(row >> 6);
        const int n = (int)(row & 63);
        const int bb = gwin >> 6, wi = gwin & 63;
        const int ipp = ((wi >> 3) << 3) + (n >> 3);
        const int jpp = ((wi & 7) << 3) + (n & 7);
        const int ii = (ipp + 4) & 63, jj = (jpp + 4) & 63;
        tok[mi] = ((long)bb << 12) + (ii << 6) + jj;
#pragma unroll
        for (int ni = 0; ni < 4; ni++) {
            const int col = wc * 64 + ni * 16 + (l >> 4) * 4;
            const float4 bz = *(const float4*)&bias[col];
            const float4 xr = *(const float4*)&x[tok[mi] * 256 + col];
            acc[mi][ni][0] += bz.x + xr.x;
            acc[mi][ni][1] += bz.y + xr.y;
            acc[mi][ni][2] += bz.z + xr.z;
            acc[mi][ni][3] += bz.w + xr.w;
#pragma unroll
            for (int j = 0; j < 4; j++) {
                ts[mi] += acc[mi][ni][j];
                tq[mi] += acc[mi][ni][j] * acc[mi][ni][j];
            }
        }
    }
#pragma unroll
    for (int mi = 0; mi < 4; mi++) {
        ts[mi] += __shfl_xor(ts[mi], 16, 64);
        tq[mi] += __shfl_xor(tq[mi], 16, 64);
        ts[mi] += __shfl_xor(ts[mi], 32, 64);
        tq[mi] += __shfl_xor(tq[mi], 32, 64);
    }
    if (l < 16) {
#pragma unroll
        for (int mi = 0; mi < 4; mi++) {
            const int r = wr * 64 + mi * 16 + l;
            sred[r * 9 + wc * 2]     = ts[mi];
            sred[r * 9 + wc * 2 + 1] = tq[mi];
        }
    }
    __syncthreads();
#pragma unroll
    for (int mi = 0; mi < 4; mi++) {
        const int r = wr * 64 + mi * 16 + (l & 15);
        float S = 0.f, Q = 0.f;
#pragma unroll
        for (int k = 0; k < 4; k++) {
            S += sred[r * 9 + k * 2];
            Q += sred[r * 9 + k * 2 + 1];
        }
        const float mean = S * (1.0f / 256.0f);
        const float var  = Q * (1.0f / 256.0f) - mean * mean;
        const float rstd = rsqrtf(var + 1e-5f);
#pragma unroll
        for (int ni = 0; ni < 4; ni++) {
            const int col = wc * 64 + ni * 16 + (l >> 4) * 4;
            const float4 gg = *(const float4*)&g2[col];
            const float4 bb = *(const float4*)&b2[col];
            bf16x4 ov;
            ov[0] = (bf16)((acc[mi][ni][0] - mean) * rstd * gg.x + bb.x);
            ov[1] = (bf16)((acc[mi][ni][1] - mean) * rstd * gg.y + bb.y);
            ov[2] = (bf16)((acc[mi][ni][2] - mean) * rstd * gg.z + bb.z);
            ov[3] = (bf16)((acc[mi][ni][3] - mean) * rstd * gg.w + bb.w);
            *(bf16x4*)&xn2[tok[mi] * 256 + col] = ov;
        }
    }
}

// ---------------- per-window attention (R8/R9 proven)
__global__ __launch_bounds__(256, 4)
void attn_kernel(const bf16* __restrict__ qkv, const bf16* __restrict__ vT,
                 const float* __restrict__ rpb, bf16* __restrict__ out)
{
    __shared__ bf16 P_lds[4][64 * 64];
    const int t = threadIdx.x;
    const int lane = t & 63;
    const int w = t >> 6;
    const int win = blockIdx.x >> 1;
    const int head = (blockIdx.x & 1) * 4 + w;
    const int wi = win & 63;
    const int lr = lane & 15;
    const int lg = lane >> 4;
    const int lk = lg * 8;
    const long base = (long)win * 64 * 768;
    const float scale = 0.17677669529663687f;   // 32^-0.5
    const int whb = (wi >> 3) << 3;
    const int wwb = (wi & 7) << 3;
    const f32x4 z4 = {0.f, 0.f, 0.f, 0.f};

    const bf16* qp  = qkv + base + head * 32;
    const bf16* kp  = qkv + base + 256 + head * 32;
    const bf16* vtp = vT + (long)win * 16384 + head * 32 * 64;

    int idm[4];
#pragma unroll
    for (int ni = 0; ni < 4; ni++) {
        const int m = ni * 16 + lr;
        const int gi2 = whb + (m >> 3), gj2 = wwb + (m & 7);
        idm[ni] = (gi2 < 56 ? 0 : (gi2 < 60 ? 1 : 2)) * 3 + (gj2 < 56 ? 0 : (gj2 < 60 ? 1 : 2));
    }

    bf16x8 aq[4], bk[4];
#pragma unroll
    for (int mi = 0; mi < 4; mi++)
        aq[mi] = *(const bf16x8*)(qp + (mi * 16 + lr) * 768 + lk);
#pragma unroll
    for (int ni = 0; ni < 4; ni++)
        bk[ni] = *(const bf16x8*)(kp + (ni * 16 + lr) * 768 + lk);

    f32x4 s[4][4];
#pragma unroll
    for (int i = 0; i < 4; i++)
#pragma unroll
        for (int j = 0; j < 4; j++) s[i][j] = z4;
#pragma unroll
    for (int mi = 0; mi < 4; mi++)
#pragma unroll
        for (int ni = 0; ni < 4; ni++)
            s[mi][ni] = __builtin_amdgcn_mfma_f32_16x16x32_bf16(aq[mi], bk[ni], s[mi][ni], 0, 0, 0);

#pragma unroll
    for (int mi = 0; mi < 4; mi++)
#pragma unroll
        for (int r = 0; r < 4; r++) {
            const int n = mi * 16 + lg * 4 + r;
            const int gi = whb + (n >> 3);
            const int gj = wwb + (n & 7);
            const int idn = (gi < 56 ? 0 : (gi < 60 ? 1 : 2)) * 3 + (gj < 56 ? 0 : (gj < 60 ? 1 : 2));
            float vals[4];
            float rowmax = -3.0e38f;
#pragma unroll
            for (int ni = 0; ni < 4; ni++) {
                const int m = ni * 16 + lr;
                const int dj = (n & 7) - (m & 7);
                const int di = (n >> 3) - (m >> 3);
                float sv = s[mi][ni][r] * scale + rpb[((dj + 7) * 15 + (di + 7)) * 8 + head];
                if (idn == idm[ni]) sv -= 100.0f;   // faithful: -100 where EQUAL
                vals[ni] = sv;
                rowmax = fmaxf(rowmax, sv);
            }
#pragma unroll
            for (int msk = 8; msk >= 1; msk >>= 1)
                rowmax = fmaxf(rowmax, __shfl_xor(rowmax, msk, 64));
            float rsum = 0.f;
#pragma unroll
            for (int ni = 0; ni < 4; ni++) {
                const float p = __expf(vals[ni] - rowmax);
                vals[ni] = p;
                rsum += p;
            }
#pragma unroll
            for (int msk = 8; msk >= 1; msk >>= 1)
                rsum += __shfl_xor(rsum, msk, 64);
            const float inv = 1.0f / rsum;
            const int swz = (n & 7) << 3;
#pragma unroll
            for (int ni = 0; ni < 4; ni++)
                P_lds[w][n * 64 + ((ni * 16 + lr) ^ swz)] = (bf16)(vals[ni] * inv);
        }

    f32x4 o[4][2];
#pragma unroll
    for (int i = 0; i < 4; i++)
#pragma unroll
        for (int j = 0; j < 2; j++) o[i][j] = z4;
#pragma unroll
    for (int kk = 0; kk < 2; kk++) {
        bf16x8 bv[2];
#pragma unroll
        for (int ni = 0; ni < 2; ni++)
            bv[ni] = *(const bf16x8*)&vtp[(ni * 16 + lr) * 64 + kk * 32 + lk];
#pragma unroll
        for (int mi = 0; mi < 4; mi++) {
            const int row = mi * 16 + lr;
            const bf16x8 ap = *(const bf16x8*)&P_lds[w][row * 64 + ((kk * 32 + lk) ^ ((row & 7) << 3))];
#pragma unroll
            for (int ni = 0; ni < 2; ni++)
                o[mi][ni] = __builtin_amdgcn_mfma_f32_16x16x32_bf16(bv[ni], ap, o[mi][ni], 0, 0, 0);
        }
    }
#pragma unroll
    for (int mi = 0; mi < 4; mi++)
#pragma unroll
        for (int ni = 0; ni < 2; ni++) {
            const int n = mi * 16 + lr;
            const int d = ni * 16 + lg * 4;
            bf16x4 ov;
            ov[0] = (bf16)o[mi][ni][0]; ov[1] = (bf16)o[mi][ni][1];
            ov[2] = (bf16)o[mi][ni][2]; ov[3] = (bf16)o[mi][ni][3];
            *(bf16x4*)(out + ((long)(win * 64 + n)) * 256 + head * 32 + d) = ov;
        }
}

extern "C" void kernel_launch(void* const* d_in, const int* in_sizes, int n_in,
                              void* d_out, int out_size, void* d_ws, size_t ws_size,
                              hipStream_t stream)
{
    (void)in_sizes; (void)n_in; (void)out_size;
    const float* x      = (const float*)d_in[0];
    const float* n1g    = (const float*)d_in[1];
    const float* n1b    = (const float*)d_in[2];
    const float* qkv_w  = (const float*)d_in[3];
    const float* qkv_b  = (const float*)d_in[4];
    const float* rpb    = (const float*)d_in[5];
    const float* proj_w = (const float*)d_in[6];
    const float* proj_b = (const float*)d_in[7];
    const float* n2g    = (const float*)d_in[8];
    const float* n2b    = (const float*)d_in[9];
    const float* fc1_w  = (const float*)d_in[10];
    const float* fc1_b  = (const float*)d_in[11];
    const float* fc2_w  = (const float*)d_in[12];
    const float* fc2_b  = (const float*)d_in[13];
    float* out = (float*)d_out;

    // workspace plan (130 MB):
    //   0..2MB weights | 2..34MB xw -> attn_o | 34..130MB qkvb | hbuf 2..130MB
    //   d_out: vT 0..32MB, xn2 32..64MB (both dead before FC2 writes out)
    char* ws = (char*)d_ws;
    bf16* qkv_wt  = (bf16*)(ws + 0);          // 768x256
    bf16* proj_wt = (bf16*)(ws + 393216);     // 256x256
    bf16* fc1_wt  = (bf16*)(ws + 524288);     // 1024x256
    bf16* fc2_wt  = (bf16*)(ws + 1048576);    // 256x1024
    bf16* xw      = (bf16*)(ws + 2097152);    // 32MB  [65536][256]
    bf16* qkvb    = (bf16*)(ws + 35651584);   // 96MB  [65536][768] (V cols unused)
    bf16* attn_o  = xw;                       // reuse xw (dead after QKV gemm)
    bf16* vT      = (bf16*)d_out;             // V^T staging in d_out[0..32MB]
    bf16* xn2     = (bf16*)d_out + 16777216;  // LN2 out in d_out[32..64MB]
    bf16* hbuf    = xw;                       // 128MB over 2..130MB (all dead)
    if (ws_size < 136314880ull) return;       // insufficient scratch

    const size_t LB  = 73728;   // 72 KB (256x128 3-stage)
    const size_t LBP = 78336;   // proj_ln2: A 24K + B 48K + sred 4.5K

    wprep_all<<<3072, 256, 0, stream>>>(qkv_w, proj_w, fc1_w, fc2_w,
                                        qkv_wt, proj_wt, fc1_wt, fc2_wt);

    ln1_window<<<16384, 256, 0, stream>>>(x, n1g, n1b, xw);
    gemm_w<0, 8><<<1536, 512, LB, stream>>>(xw, qkv_wt, qkv_b, qkvb, 768, nullptr, vT, 6, 1536);
    attn_kernel<<<2048, 256, 0, stream>>>(qkvb, vT, rpb, attn_o);
    proj_ln2<<<512, 512, LBP, stream>>>(attn_o, proj_wt, proj_b, x, n2g, n2b, xn2, 512);
    gemm_w<2, 8><<<2048, 512, LB, stream>>>(xn2, fc1_wt, fc1_b, hbuf, 1024, nullptr, nullptr, 8, 2048);
    gemm_w<3, 32><<<512, 512, LB, stream>>>(hbuf, fc2_wt, fc2_b, out, 256, x, nullptr, 2, 512);
}

// Round 14
// 274.844 us; speedup vs baseline: 1.2058x; 1.0240x over previous
//
#include <hip/hip_runtime.h>
#include <math.h>

typedef __bf16 bf16;
typedef __bf16 bf16x4 __attribute__((ext_vector_type(4)));
typedef __bf16 bf16x8 __attribute__((ext_vector_type(8)));
typedef float f32x4 __attribute__((ext_vector_type(4)));

#define AS1 __attribute__((address_space(1)))
#define AS3 __attribute__((address_space(3)))

__device__ __forceinline__ void gload_lds16(const bf16* g, bf16* l) {
    __builtin_amdgcn_global_load_lds((const AS1 void*)g, (AS3 void*)l, 16, 0, 0);
}
__device__ __forceinline__ void gload_lds16c(const char* g, char* l) {
    __builtin_amdgcn_global_load_lds((const AS1 void*)g, (AS3 void*)l, 16, 0, 0);
}

__device__ __forceinline__ float gelu_fast(float v) {
    const float u = 1.5957691216057308f * (v + 0.044715f * v * v * v);
    return v / (1.0f + __expf(-u));
}

// pack 4 floats to 4 fp8-e4m3 bytes
__device__ __forceinline__ unsigned cvt_fp8x4(float a, float b, float c, float d) {
    int r = 0;
    r = __builtin_amdgcn_cvt_pk_fp8_f32(a, b, r, false);
    r = __builtin_amdgcn_cvt_pk_fp8_f32(c, d, r, true);
    return (unsigned)r;
}

// ---------------- all weight transposes + cast in ONE launch
// qkv/proj/fc1 -> bf16 [N][K]; fc2 -> fp8 e4m3 [N][K] scaled x16
__global__ __launch_bounds__(256)
void wprep_all(const float* __restrict__ qkv_w, const float* __restrict__ proj_w,
               const float* __restrict__ fc1_w, const float* __restrict__ fc2_w,
               bf16* __restrict__ qkv_wt, bf16* __restrict__ proj_wt,
               bf16* __restrict__ fc1_wt, char* __restrict__ fc2_wq)
{
    int idx = blockIdx.x * 256 + threadIdx.x;
    if (idx < 524288) {
        const float* src; bf16* dst; int K, N;
        if (idx < 196608)      { src = qkv_w;  dst = qkv_wt;  K = 256; N = 768; }
        else if (idx < 262144) { idx -= 196608; src = proj_w; dst = proj_wt; K = 256; N = 256; }
        else                   { idx -= 262144; src = fc1_w;  dst = fc1_wt;  K = 256; N = 1024; }
        const int k = idx / N, n = idx % N;
        dst[(long)n * K + k] = (bf16)src[idx];
    } else {
        idx -= 524288;                       // fc2: src fp32 [1024][256]
        const int k = idx >> 8, n = idx & 255;
        const int r = __builtin_amdgcn_cvt_pk_fp8_f32(fc2_w[idx] * 16.0f, 0.f, 0, false);
        fc2_wq[(long)n * 1024 + k] = (char)(r & 0xFF);
    }
}

// ---------------- LN1 + cyclic shift(-4,-4) + window partition -> xw bf16 [B*64win][64][256]
__global__ __launch_bounds__(256)
void ln1_window(const float* __restrict__ x, const float* __restrict__ g,
                const float* __restrict__ be, bf16* __restrict__ xw)
{
    const int t = threadIdx.x;
    const int lane = t & 63;
    const int w = t >> 6;
    const long tok = (long)blockIdx.x * 4 + w;
    const float4 v = ((const float4*)(x + tok * 256))[lane];
    float sum = v.x + v.y + v.z + v.w;
    float sq  = v.x * v.x + v.y * v.y + v.z * v.z + v.w * v.w;
#pragma unroll
    for (int m = 32; m >= 1; m >>= 1) {
        sum += __shfl_xor(sum, m, 64);
        sq  += __shfl_xor(sq,  m, 64);
    }
    const float mean = sum * (1.0f / 256.0f);
    const float var  = sq * (1.0f / 256.0f) - mean * mean;
    const float rstd = rsqrtf(var + 1e-5f);
    const float4 gv = ((const float4*)g)[lane];
    const float4 bv = ((const float4*)be)[lane];
    bf16x4 ov;
    ov[0] = (bf16)((v.x - mean) * rstd * gv.x + bv.x);
    ov[1] = (bf16)((v.y - mean) * rstd * gv.y + bv.y);
    ov[2] = (bf16)((v.z - mean) * rstd * gv.z + bv.z);
    ov[3] = (bf16)((v.w - mean) * rstd * gv.w + bv.w);
    const int b = (int)(tok >> 12);
    const int l = (int)(tok & 4095);
    const int i = l >> 6, j = l & 63;
    const int ip = (i + 60) & 63, jp = (j + 60) & 63;   // shifted coords
    const int winl = ((ip >> 3) << 3) + (jp >> 3);
    const int n = ((ip & 7) << 3) + (jp & 7);
    const long drow = ((long)b * 64 + winl) * 64 + n;
    *(bf16x4*)(xw + drow * 256 + lane * 4) = ov;
}

// ---------------- GEMM 256x128 tile (QKV / FC1) — R11 proven structure.
// EPI 0: +bias -> bf16 qkvb (Q/K via LDS-transpose coalesced path); V -> vT
// EPI 2: +bias, fast GELU, x16 -> FP8 out via transpose path (FC1 -> hbuf)
template<int EPI, int KT>
__global__ __launch_bounds__(512, 2)
void gemm_w(const bf16* __restrict__ A, const bf16* __restrict__ Bt,
            const float* __restrict__ bias, void* __restrict__ outp,
            int N, const float* __restrict__ xres, void* __restrict__ aux,
            int gx, int nb)
{
    constexpr int K = KT * 32;
    extern __shared__ bf16 lds[];
    bf16* sA = lds;                 // 3 bufs x 8192 elems (256x32)
    bf16* sB = lds + 3 * 8192;      // 3 bufs x 4096 elems (128x32)
    const int t = threadIdx.x;
    const int l = t & 63;
    const int w = t >> 6;
    const int wr = w >> 1, wc = w & 1;
    const int q = nb >> 3;
    const int id = ((int)blockIdx.x & 7) * q + ((int)blockIdx.x >> 3);
    const long m0 = (long)(id / gx) * 256;
    const long n0 = (long)(id % gx) * 128;

    const bf16* asrcp[2]; bf16* adstp[2];
#pragma unroll
    for (int j = 0; j < 2; j++) {
        const int idx = j * 512 + t;
        const int p = idx >> 3, s = idx & 7;
        const int sl = s ^ (p & 7);
        const int row = 2 * p + (sl >> 2);
        const int ce = (sl & 3) * 8;
        asrcp[j] = A + (m0 + row) * (long)K + ce;
        adstp[j] = &sA[idx * 8];
    }
    const bf16* bsrcp; bf16* bdstp;
    {
        const int p = t >> 3, s = t & 7;
        const int sl = s ^ (p & 7);
        const int row = 2 * p + (sl >> 2);
        const int ce = (sl & 3) * 8;
        bsrcp = Bt + (n0 + row) * (long)K + ce;
        bdstp = &sB[t * 8];
    }

    const int c = l >> 4;
    int eA[4], eB[4];
#pragma unroll
    for (int i = 0; i < 4; i++) {
        const int rowA = wr * 64 + (l & 15) + i * 16;
        const int pa = rowA >> 1;
        eA[i] = (pa * 8 + ((((rowA & 1) << 2) + c) ^ (pa & 7))) * 8;
        const int rowB = wc * 64 + (l & 15) + i * 16;
        const int pb = rowB >> 1;
        eB[i] = (pb * 8 + ((((rowB & 1) << 2) + c) ^ (pb & 7))) * 8;
    }

    f32x4 acc[4][4];
#pragma unroll
    for (int i = 0; i < 4; i++)
#pragma unroll
        for (int j = 0; j < 4; j++) acc[i][j] = (f32x4){0.f, 0.f, 0.f, 0.f};

#define STAGE(bufi, ko)                                                        \
    do {                                                                       \
        gload_lds16(asrcp[0] + (ko), adstp[0] + (bufi) * 8192);                \
        gload_lds16(asrcp[1] + (ko), adstp[1] + (bufi) * 8192);                \
        gload_lds16(bsrcp + (ko), bdstp + (bufi) * 4096);                      \
    } while (0)

    STAGE(0, 0);
    STAGE(1, 32);

#pragma unroll
    for (int kt = 0; kt < KT; ++kt) {
        const int buf = kt % 3;
        if (kt < KT - 1)
            asm volatile("s_waitcnt vmcnt(3)" ::: "memory");
        else
            asm volatile("s_waitcnt vmcnt(0)" ::: "memory");
        __builtin_amdgcn_s_barrier();
        __builtin_amdgcn_sched_barrier(0);
        if (kt + 2 < KT)
            STAGE((kt + 2) % 3, (kt + 2) * 32);
        bf16x8 av[4], bv[4];
#pragma unroll
        for (int ni = 0; ni < 4; ni++)
            bv[ni] = *(const bf16x8*)&sB[buf * 4096 + eB[ni]];
#pragma unroll
        for (int mi = 0; mi < 4; mi++)
            av[mi] = *(const bf16x8*)&sA[buf * 8192 + eA[mi]];
#pragma unroll
        for (int mi = 0; mi < 4; mi++)
#pragma unroll
            for (int ni = 0; ni < 4; ni++)
                acc[mi][ni] = __builtin_amdgcn_mfma_f32_16x16x32_bf16(
                    bv[ni], av[mi], acc[mi][ni], 0, 0, 0);
    }
#undef STAGE

    // ---- epilogue ----
    if constexpr (EPI == 2) {
        // fp8 transpose path: per-wave 64 rows x 64 cols (1B) staged in LDS
        __syncthreads();
        char* wlds = (char*)(lds) + w * 4608;     // 64 rows x 72B per wave
#pragma unroll
        for (int mi = 0; mi < 4; mi++)
#pragma unroll
            for (int ni = 0; ni < 4; ni++) {
                const int colb = ni * 16 + (l >> 4) * 4;   // fp8 byte col 0..63
                const int rowl = mi * 16 + (l & 15);
                const float4 bz = *(const float4*)&bias[n0 + wc * 64 + colb];
                const unsigned pk = cvt_fp8x4(
                    gelu_fast(acc[mi][ni][0] + bz.x) * 16.0f,
                    gelu_fast(acc[mi][ni][1] + bz.y) * 16.0f,
                    gelu_fast(acc[mi][ni][2] + bz.z) * 16.0f,
                    gelu_fast(acc[mi][ni][3] + bz.w) * 16.0f);
                *(unsigned*)(wlds + rowl * 72 + colb) = pk;
            }
        char* outb = (char*)outp;
#pragma unroll
        for (int j = 0; j < 8; j++) {
            const int r = j * 8 + (l >> 3);
            const long vr = *(const long*)(wlds + r * 72 + (l & 7) * 8);
            const long row = m0 + wr * 64 + r;
            *(long*)&outb[row * (long)N + n0 + wc * 64 + (l & 7) * 8] = vr;
        }
    } else {
        const bool transpose_path = (n0 < 512);
        if (transpose_path) {
            __syncthreads();
            char* wlds = (char*)(lds) + w * 8704;     // 64 rows x 136B per wave
#pragma unroll
            for (int mi = 0; mi < 4; mi++)
#pragma unroll
                for (int ni = 0; ni < 4; ni++) {
                    const int colb = (ni * 16 + (l >> 4) * 4) * 2;
                    const int rowl = mi * 16 + (l & 15);
                    const float4 bz = *(const float4*)&bias[n0 + wc * 64 + ni * 16 + (l >> 4) * 4];
                    bf16x4 ov;
                    ov[0] = (bf16)(acc[mi][ni][0] + bz.x);
                    ov[1] = (bf16)(acc[mi][ni][1] + bz.y);
                    ov[2] = (bf16)(acc[mi][ni][2] + bz.z);
                    ov[3] = (bf16)(acc[mi][ni][3] + bz.w);
                    *(bf16x4*)(wlds + rowl * 136 + (colb ^ ((rowl & 7) << 4))) = ov;
                }
            bf16* outb = (bf16*)outp;
#pragma unroll
            for (int j = 0; j < 8; j++) {
                const int r = j * 8 + (l >> 3);
                const bf16x8 vr = *(const bf16x8*)(wlds + r * 136 + (((l & 7) * 16) ^ ((r & 7) << 4)));
                const long row = m0 + wr * 64 + r;
                const int col = (int)(n0 + wc * 64 + (l & 7) * 8);
                *(bf16x8*)&outb[row * N + col] = vr;
            }
        } else {
#pragma unroll
            for (int mi = 0; mi < 4; mi++)
#pragma unroll
                for (int ni = 0; ni < 4; ni++) {
                    const long row = m0 + wr * 64 + mi * 16 + (l & 15);
                    const int col = (int)(n0 + wc * 64 + ni * 16 + (l >> 4) * 4);
                    const float4 bz = *(const float4*)&bias[col];
                    // V columns -> vT[win][d][key]
                    bf16* vt = (bf16*)aux;
                    const int win = (int)(row >> 6);
                    const int n = (int)(row & 63);
#pragma unroll
                    for (int j = 0; j < 4; j++)
                        vt[(long)win * 16384 + (col - 512 + j) * 64 + n] =
                            (bf16)(acc[mi][ni][j] + ((const float*)&bz)[j]);
                }
        }
    }
    (void)xres; (void)aux;
}

// ---------------- FC2 fp8: out = x + (hbuf_fp8 @ W2_fp8^T)/256 + b2
// 256x128 tile, 8 waves, KT=32 of K=32 fp8 bytes, 3-stage counted pipeline.
// LDS chunk swizzle: logical (row, h) -> slot s = 2*(row&7) + (h ^ ((row>>2)&1))
// within each 8-row group (16 chunks); fragment reads are 2-way (free).
__global__ __launch_bounds__(512, 2)
void gemm_fc2(const char* __restrict__ A, const char* __restrict__ Bq,
              const float* __restrict__ bias, float* __restrict__ out,
              const float* __restrict__ xres, int nb)
{
    constexpr int KT = 32;
    extern __shared__ char lds8[];
    char* sA8 = lds8;                // 3 bufs x 8192 B (256 rows x 32 B)
    char* sB8 = lds8 + 3 * 8192;     // 3 bufs x 4096 B (128 rows x 32 B)
    const int t = threadIdx.x;
    const int l = t & 63;
    const int w = t >> 6;
    const int wr = w >> 1, wc = w & 1;
    const int q = nb >> 3;
    const int id = ((int)blockIdx.x & 7) * q + ((int)blockIdx.x >> 3);
    const long m0 = (long)(id / 2) * 256;
    const long n0 = (long)(id % 2) * 128;

    // staging: A 512 chunks (1/thread); B 256 chunks (threads 0..255)
    const char* asrc; char* adst;
    {
        const int g = t >> 4, s = t & 15;
        const int r = s >> 1;
        const int h = (s & 1) ^ ((r >> 2) & 1);
        const int row = g * 8 + r;
        asrc = A + (m0 + row) * 1024 + h * 16;
        adst = sA8 + t * 16;
    }
    const char* bsrc = nullptr; char* bdst = nullptr;
    if (t < 256) {
        const int g = t >> 4, s = t & 15;
        const int r = s >> 1;
        const int h = (s & 1) ^ ((r >> 2) & 1);
        const int row = g * 8 + r;
        bsrc = Bq + (n0 + row) * 1024 + h * 16;
        bdst = sB8 + t * 16;
    }

    // fragment byte-offsets
    const int c = l >> 4;
    int eA[4], eB[4];
#pragma unroll
    for (int i = 0; i < 4; i++) {
        const int rowA = wr * 64 + (l & 15) + i * 16;
        const int rA = rowA & 7;
        eA[i] = (rowA >> 3) * 256 + (2 * rA + ((c >> 1) ^ ((rA >> 2) & 1))) * 16 + (c & 1) * 8;
        const int rowB = wc * 64 + (l & 15) + i * 16;
        const int rB = rowB & 7;
        eB[i] = (rowB >> 3) * 256 + (2 * rB + ((c >> 1) ^ ((rB >> 2) & 1))) * 16 + (c & 1) * 8;
    }

    f32x4 acc[4][4];
#pragma unroll
    for (int i = 0; i < 4; i++)
#pragma unroll
        for (int j = 0; j < 4; j++) acc[i][j] = (f32x4){0.f, 0.f, 0.f, 0.f};

#define STAGE2(bufi, ko)                                                       \
    do {                                                                       \
        gload_lds16c(asrc + (ko), adst + (bufi) * 8192);                       \
        if (t < 256) gload_lds16c(bsrc + (ko), bdst + (bufi) * 4096);          \
    } while (0)

    STAGE2(0, 0);
    STAGE2(1, 32);

#pragma unroll
    for (int kt = 0; kt < KT; ++kt) {
        const int buf = kt % 3;
        if (kt < KT - 1) {
            if (w < 4) asm volatile("s_waitcnt vmcnt(2)" ::: "memory");
            else       asm volatile("s_waitcnt vmcnt(1)" ::: "memory");
        } else {
            asm volatile("s_waitcnt vmcnt(0)" ::: "memory");
        }
        __builtin_amdgcn_s_barrier();
        __builtin_amdgcn_sched_barrier(0);
        if (kt + 2 < KT)
            STAGE2((kt + 2) % 3, (kt + 2) * 32);
        long av[4], bv[4];
#pragma unroll
        for (int ni = 0; ni < 4; ni++)
            bv[ni] = *(const long*)&sB8[buf * 4096 + eB[ni]];
#pragma unroll
        for (int mi = 0; mi < 4; mi++)
            av[mi] = *(const long*)&sA8[buf * 8192 + eA[mi]];
#pragma unroll
        for (int mi = 0; mi < 4; mi++)
#pragma unroll
            for (int ni = 0; ni < 4; ni++)
                acc[mi][ni] = __builtin_amdgcn_mfma_f32_16x16x32_fp8_fp8(
                    bv[ni], av[mi], acc[mi][ni], 0, 0, 0);
    }
#undef STAGE2

    // epilogue: /256 + bias + x residual -> f32 out
#pragma unroll
    for (int mi = 0; mi < 4; mi++)
#pragma unroll
        for (int ni = 0; ni < 4; ni++) {
            const long row = m0 + wr * 64 + mi * 16 + (l & 15);
            const int col = (int)(n0 + wc * 64 + ni * 16 + (l >> 4) * 4);
            const float4 bz = *(const float4*)&bias[col];
            const float4 xr = *(const float4*)&xres[row * 256 + col];
            float4 ov;
            ov.x = acc[mi][ni][0] * 0.00390625f + bz.x + xr.x;
            ov.y = acc[mi][ni][1] * 0.00390625f + bz.y + xr.y;
            ov.z = acc[mi][ni][2] * 0.00390625f + bz.z + xr.z;
            ov.w = acc[mi][ni][3] * 0.00390625f + bz.w + xr.w;
            *(float4*)&out[row * 256 + col] = ov;
        }
}

// ---------------- FUSED proj + LN2 (R13 proven)
__global__ __launch_bounds__(512, 2)
void proj_ln2(const bf16* __restrict__ A, const bf16* __restrict__ Bt,
              const float* __restrict__ bias, const float* __restrict__ x,
              const float* __restrict__ g2, const float* __restrict__ b2,
              bf16* __restrict__ xn2, int nb)
{
    extern __shared__ bf16 lds[];
    bf16* sA = lds;                       // 3 bufs x 4096 elems (128x32)
    bf16* sB = lds + 3 * 4096;            // 3 bufs x 8192 elems (256x32)
    float* sred = (float*)(lds + 3 * 4096 + 3 * 8192);   // [128][9] floats
    const int t = threadIdx.x;
    const int l = t & 63;
    const int w = t >> 6;
    const int wr = w >> 2, wc = w & 3;    // 2 x 4 wave grid; wave = 64r x 64c
    const int q = nb >> 3;
    const int id = ((int)blockIdx.x & 7) * q + ((int)blockIdx.x >> 3);
    const long m0 = (long)id * 128;

    const bf16* asrcp; bf16* adstp;
    {
        const int p = t >> 3, s = t & 7;
        const int sl = s ^ (p & 7);
        const int row = 2 * p + (sl >> 2);
        const int ce = (sl & 3) * 8;
        asrcp = A + (m0 + row) * 256 + ce;
        adstp = &sA[t * 8];
    }
    const bf16* bsrcp[2]; bf16* bdstp[2];
#pragma unroll
    for (int j = 0; j < 2; j++) {
        const int idx = j * 512 + t;
        const int p = idx >> 3, s = idx & 7;
        const int sl = s ^ (p & 7);
        const int row = 2 * p + (sl >> 2);
        const int ce = (sl & 3) * 8;
        bsrcp[j] = Bt + (long)row * 256 + ce;
        bdstp[j] = &sB[idx * 8];
    }

    const int c = l >> 4;
    int eA[4], eB[4];
#pragma unroll
    for (int i = 0; i < 4; i++) {
        const int rowA = wr * 64 + (l & 15) + i * 16;
        const int pa = rowA >> 1;
        eA[i] = (pa * 8 + ((((rowA & 1) << 2) + c) ^ (pa & 7))) * 8;
        const int rowB = wc * 64 + (l & 15) + i * 16;
        const int pb = rowB >> 1;
        eB[i] = (pb * 8 + ((((rowB & 1) << 2) + c) ^ (pb & 7))) * 8;
    }

    f32x4 acc[4][4];
#pragma unroll
    for (int i = 0; i < 4; i++)
#pragma unroll
        for (int j = 0; j < 4; j++) acc[i][j] = (f32x4){0.f, 0.f, 0.f, 0.f};

#define STAGE(bufi, ko)                                                        \
    do {                                                                       \
        gload_lds16(asrcp + (ko), adstp + (bufi) * 4096);                      \
        gload_lds16(bsrcp[0] + (ko), bdstp[0] + (bufi) * 8192);                \
        gload_lds16(bsrcp[1] + (ko), bdstp[1] + (bufi) * 8192);                \
    } while (0)

    STAGE(0, 0);
    STAGE(1, 32);

#pragma unroll
    for (int kt = 0; kt < 8; ++kt) {
        const int buf = kt % 3;
        if (kt < 7)
            asm volatile("s_waitcnt vmcnt(3)" ::: "memory");
        else
            asm volatile("s_waitcnt vmcnt(0)" ::: "memory");
        __builtin_amdgcn_s_barrier();
        __builtin_amdgcn_sched_barrier(0);
        if (kt + 2 < 8)
            STAGE((kt + 2) % 3, (kt + 2) * 32);
        bf16x8 av[4], bv[4];
#pragma unroll
        for (int ni = 0; ni < 4; ni++)
            bv[ni] = *(const bf16x8*)&sB[buf * 8192 + eB[ni]];
#pragma unroll
        for (int mi = 0; mi < 4; mi++)
            av[mi] = *(const bf16x8*)&sA[buf * 4096 + eA[mi]];
#pragma unroll
        for (int mi = 0; mi < 4; mi++)
#pragma unroll
            for (int ni = 0; ni < 4; ni++)
                acc[mi][ni] = __builtin_amdgcn_mfma_f32_16x16x32_bf16(
                    bv[ni], av[mi], acc[mi][ni], 0, 0, 0);
    }
#undef STAGE

    float ts[4] = {0.f, 0.f, 0.f, 0.f}, tq[4] = {0.f, 0.f, 0.f, 0.f};
    long tok[4];
#pragma unroll
    for (int mi = 0; mi < 4; mi++) {
        const long row = m0 + wr * 64 + mi * 16 + (l & 15);
        const int gwin = (int)(row >> 6);
        const int n = (int)(row & 63);
        const int bb = gwin >> 6, wi = gwin & 63;
        const int ipp = ((wi >> 3) << 3) + (n >> 3);
        const int jpp = ((wi & 7) << 3) + (n & 7);
        const int ii = (ipp + 4) & 63, jj = (jpp + 4) & 63;
        tok[mi] = ((long)bb << 12) + (ii << 6) + jj;
#pragma unroll
        for (int ni = 0; ni < 4; ni++) {
            const int col = wc * 64 + ni * 16 + (l >> 4) * 4;
            const float4 bz = *(const float4*)&bias[col];
            const float4 xr = *(const float4*)&x[tok[mi] * 256 + col];
            acc[mi][ni][0] += bz.x + xr.x;
            acc[mi][ni][1] += bz.y + xr.y;
            acc[mi][ni][2] += bz.z + xr.z;
            acc[mi][ni][3] += bz.w + xr.w;
#pragma unroll
            for (int j = 0; j < 4; j++) {
                ts[mi] += acc[mi][ni][j];
                tq[mi] += acc[mi][ni][j] * acc[mi][ni][j];
            }
        }
    }
#pragma unroll
    for (int mi = 0; mi < 4; mi++) {
        ts[mi] += __shfl_xor(ts[mi], 16, 64);
        tq[mi] += __shfl_xor(tq[mi], 16, 64);
        ts[mi] += __shfl_xor(ts[mi], 32, 64);
        tq[mi] += __shfl_xor(tq[mi], 32, 64);
    }
    if (l < 16) {
#pragma unroll
        for (int mi = 0; mi < 4; mi++) {
            const int r = wr * 64 + mi * 16 + l;
            sred[r * 9 + wc * 2]     = ts[mi];
            sred[r * 9 + wc * 2 + 1] = tq[mi];
        }
    }
    __syncthreads();
#pragma unroll
    for (int mi = 0; mi < 4; mi++) {
        const int r = wr * 64 + mi * 16 + (l & 15);
        float S = 0.f, Q = 0.f;
#pragma unroll
        for (int k = 0; k < 4; k++) {
            S += sred[r * 9 + k * 2];
            Q += sred[r * 9 + k * 2 + 1];
        }
        const float mean = S * (1.0f / 256.0f);
        const float var  = Q * (1.0f / 256.0f) - mean * mean;
        const float rstd = rsqrtf(var + 1e-5f);
#pragma unroll
        for (int ni = 0; ni < 4; ni++) {
            const int col = wc * 64 + ni * 16 + (l >> 4) * 4;
            const float4 gg = *(const float4*)&g2[col];
            const float4 bb = *(const float4*)&b2[col];
            bf16x4 ov;
            ov[0] = (bf16)((acc[mi][ni][0] - mean) * rstd * gg.x + bb.x);
            ov[1] = (bf16)((acc[mi][ni][1] - mean) * rstd * gg.y + bb.y);
            ov[2] = (bf16)((acc[mi][ni][2] - mean) * rstd * gg.z + bb.z);
            ov[3] = (bf16)((acc[mi][ni][3] - mean) * rstd * gg.w + bb.w);
            *(bf16x4*)&xn2[tok[mi] * 256 + col] = ov;
        }
    }
}

// ---------------- per-window attention (R8/R9 proven)
__global__ __launch_bounds__(256, 4)
void attn_kernel(const bf16* __restrict__ qkv, const bf16* __restrict__ vT,
                 const float* __restrict__ rpb, bf16* __restrict__ out)
{
    __shared__ bf16 P_lds[4][64 * 64];
    const int t = threadIdx.x;
    const int lane = t & 63;
    const int w = t >> 6;
    const int win = blockIdx.x >> 1;
    const int head = (blockIdx.x & 1) * 4 + w;
    const int wi = win & 63;
    const int lr = lane & 15;
    const int lg = lane >> 4;
    const int lk = lg * 8;
    const long base = (long)win * 64 * 768;
    const float scale = 0.17677669529663687f;   // 32^-0.5
    const int whb = (wi >> 3) << 3;
    const int wwb = (wi & 7) << 3;
    const f32x4 z4 = {0.f, 0.f, 0.f, 0.f};

    const bf16* qp  = qkv + base + head * 32;
    const bf16* kp  = qkv + base + 256 + head * 32;
    const bf16* vtp = vT + (long)win * 16384 + head * 32 * 64;

    int idm[4];
#pragma unroll
    for (int ni = 0; ni < 4; ni++) {
        const int m = ni * 16 + lr;
        const int gi2 = whb + (m >> 3), gj2 = wwb + (m & 7);
        idm[ni] = (gi2 < 56 ? 0 : (gi2 < 60 ? 1 : 2)) * 3 + (gj2 < 56 ? 0 : (gj2 < 60 ? 1 : 2));
    }

    bf16x8 aq[4], bk[4];
#pragma unroll
    for (int mi = 0; mi < 4; mi++)
        aq[mi] = *(const bf16x8*)(qp + (mi * 16 + lr) * 768 + lk);
#pragma unroll
    for (int ni = 0; ni < 4; ni++)
        bk[ni] = *(const bf16x8*)(kp + (ni * 16 + lr) * 768 + lk);

    f32x4 s[4][4];
#pragma unroll
    for (int i = 0; i < 4; i++)
#pragma unroll
        for (int j = 0; j < 4; j++) s[i][j] = z4;
#pragma unroll
    for (int mi = 0; mi < 4; mi++)
#pragma unroll
        for (int ni = 0; ni < 4; ni++)
            s[mi][ni] = __builtin_amdgcn_mfma_f32_16x16x32_bf16(aq[mi], bk[ni], s[mi][ni], 0, 0, 0);

#pragma unroll
    for (int mi = 0; mi < 4; mi++)
#pragma unroll
        for (int r = 0; r < 4; r++) {
            const int n = mi * 16 + lg * 4 + r;
            const int gi = whb + (n >> 3);
            const int gj = wwb + (n & 7);
            const int idn = (gi < 56 ? 0 : (gi < 60 ? 1 : 2)) * 3 + (gj < 56 ? 0 : (gj < 60 ? 1 : 2));
            float vals[4];
            float rowmax = -3.0e38f;
#pragma unroll
            for (int ni = 0; ni < 4; ni++) {
                const int m = ni * 16 + lr;
                const int dj = (n & 7) - (m & 7);
                const int di = (n >> 3) - (m >> 3);
                float sv = s[mi][ni][r] * scale + rpb[((dj + 7) * 15 + (di + 7)) * 8 + head];
                if (idn == idm[ni]) sv -= 100.0f;   // faithful: -100 where EQUAL
                vals[ni] = sv;
                rowmax = fmaxf(rowmax, sv);
            }
#pragma unroll
            for (int msk = 8; msk >= 1; msk >>= 1)
                rowmax = fmaxf(rowmax, __shfl_xor(rowmax, msk, 64));
            float rsum = 0.f;
#pragma unroll
            for (int ni = 0; ni < 4; ni++) {
                const float p = __expf(vals[ni] - rowmax);
                vals[ni] = p;
                rsum += p;
            }
#pragma unroll
            for (int msk = 8; msk >= 1; msk >>= 1)
                rsum += __shfl_xor(rsum, msk, 64);
            const float inv = 1.0f / rsum;
            const int swz = (n & 7) << 3;
#pragma unroll
            for (int ni = 0; ni < 4; ni++)
                P_lds[w][n * 64 + ((ni * 16 + lr) ^ swz)] = (bf16)(vals[ni] * inv);
        }

    f32x4 o[4][2];
#pragma unroll
    for (int i = 0; i < 4; i++)
#pragma unroll
        for (int j = 0; j < 2; j++) o[i][j] = z4;
#pragma unroll
    for (int kk = 0; kk < 2; kk++) {
        bf16x8 bv[2];
#pragma unroll
        for (int ni = 0; ni < 2; ni++)
            bv[ni] = *(const bf16x8*)&vtp[(ni * 16 + lr) * 64 + kk * 32 + lk];
#pragma unroll
        for (int mi = 0; mi < 4; mi++) {
            const int row = mi * 16 + lr;
            const bf16x8 ap = *(const bf16x8*)&P_lds[w][row * 64 + ((kk * 32 + lk) ^ ((row & 7) << 3))];
#pragma unroll
            for (int ni = 0; ni < 2; ni++)
                o[mi][ni] = __builtin_amdgcn_mfma_f32_16x16x32_bf16(bv[ni], ap, o[mi][ni], 0, 0, 0);
        }
    }
#pragma unroll
    for (int mi = 0; mi < 4; mi++)
#pragma unroll
        for (int ni = 0; ni < 2; ni++) {
            const int n = mi * 16 + lr;
            const int d = ni * 16 + lg * 4;
            bf16x4 ov;
            ov[0] = (bf16)o[mi][ni][0]; ov[1] = (bf16)o[mi][ni][1];
            ov[2] = (bf16)o[mi][ni][2]; ov[3] = (bf16)o[mi][ni][3];
            *(bf16x4*)(out + ((long)(win * 64 + n)) * 256 + head * 32 + d) = ov;
        }
}

extern "C" void kernel_launch(void* const* d_in, const int* in_sizes, int n_in,
                              void* d_out, int out_size, void* d_ws, size_t ws_size,
                              hipStream_t stream)
{
    (void)in_sizes; (void)n_in; (void)out_size;
    const float* x      = (const float*)d_in[0];
    const float* n1g    = (const float*)d_in[1];
    const float* n1b    = (const float*)d_in[2];
    const float* qkv_w  = (const float*)d_in[3];
    const float* qkv_b  = (const float*)d_in[4];
    const float* rpb    = (const float*)d_in[5];
    const float* proj_w = (const float*)d_in[6];
    const float* proj_b = (const float*)d_in[7];
    const float* n2g    = (const float*)d_in[8];
    const float* n2b    = (const float*)d_in[9];
    const float* fc1_w  = (const float*)d_in[10];
    const float* fc1_b  = (const float*)d_in[11];
    const float* fc2_w  = (const float*)d_in[12];
    const float* fc2_b  = (const float*)d_in[13];
    float* out = (float*)d_out;

    // workspace (130 MB): 0..2MB weights | 2..34MB xw->attn_o | 34..130MB qkvb
    //   hbuf fp8 64MB @ 2..66MB (xw/attn_o + qkvb head both dead at FC1)
    //   d_out: vT 0..32MB, xn2 32..64MB (dead before FC2 writes out)
    char* ws = (char*)d_ws;
    bf16* qkv_wt  = (bf16*)(ws + 0);          // 768x256 bf16
    bf16* proj_wt = (bf16*)(ws + 393216);     // 256x256 bf16
    bf16* fc1_wt  = (bf16*)(ws + 524288);     // 1024x256 bf16
    char* fc2_wq  = (char*)(ws + 1048576);    // 256x1024 fp8 (x16)
    bf16* xw      = (bf16*)(ws + 2097152);    // 32MB  [65536][256]
    bf16* qkvb    = (bf16*)(ws + 35651584);   // 96MB  [65536][768] (V cols unused)
    bf16* attn_o  = xw;                       // reuse xw (dead after QKV gemm)
    bf16* vT      = (bf16*)d_out;             // V^T staging in d_out[0..32MB]
    bf16* xn2     = (bf16*)d_out + 16777216;  // LN2 out in d_out[32..64MB]
    char* hbuf8   = (char*)(ws + 2097152);    // 64MB fp8 [65536][1024]
    if (ws_size < 136314880ull) return;       // insufficient scratch

    const size_t LB  = 73728;   // 72 KB (256x128 3-stage)
    const size_t LBP = 78336;   // proj_ln2
    const size_t LBF = 36864;   // gemm_fc2 fp8

    wprep_all<<<3072, 256, 0, stream>>>(qkv_w, proj_w, fc1_w, fc2_w,
                                        qkv_wt, proj_wt, fc1_wt, fc2_wq);

    ln1_window<<<16384, 256, 0, stream>>>(x, n1g, n1b, xw);
    gemm_w<0, 8><<<1536, 512, LB, stream>>>(xw, qkv_wt, qkv_b, qkvb, 768, nullptr, vT, 6, 1536);
    attn_kernel<<<2048, 256, 0, stream>>>(qkvb, vT, rpb, attn_o);
    proj_ln2<<<512, 512, LBP, stream>>>(attn_o, proj_wt, proj_b, x, n2g, n2b, xn2, 512);
    gemm_w<2, 8><<<2048, 512, LB, stream>>>(xn2, fc1_wt, fc1_b, hbuf8, 1024, nullptr, nullptr, 8, 2048);
    gemm_fc2<<<512, 512, LBF, stream>>>(hbuf8, fc2_wq, fc2_b, out, x, 512);
}